// Round 7
// baseline (25344.437 us; speedup 1.0000x reference)
//
#include <hip/hip_runtime.h>
#include <cfloat>

#define BB 16
#define DD 512
#define TT 2048
#define QQ 8
#define NN 1024
#define MM 16
#define RS 520        // resid LDS row stride in floats (16B-aligned)
#define MARGIN 1e-3f  // >= 2*|s_ap - s_ex| bound (~1.6e-4), generous

// ---- validated numpy-semantics helpers (DO NOT TOUCH: matched np exactly) ----
__device__ __forceinline__ float np_block128_sq(const float* a) {
    float r[8];
    #pragma unroll
    for (int j = 0; j < 8; ++j) r[j] = __fmul_rn(a[j], a[j]);
    #pragma unroll
    for (int i = 8; i < 128; i += 8)
        #pragma unroll
        for (int j = 0; j < 8; ++j) r[j] = __fadd_rn(r[j], __fmul_rn(a[i + j], a[i + j]));
    return __fadd_rn(__fadd_rn(__fadd_rn(r[0], r[1]), __fadd_rn(r[2], r[3])),
                     __fadd_rn(__fadd_rn(r[4], r[5]), __fadd_rn(r[6], r[7])));
}
__device__ __forceinline__ float np_sum_sq_512(const float* p) {
    const float b0 = np_block128_sq(p);
    const float b1 = np_block128_sq(p + 128);
    const float b2 = np_block128_sq(p + 256);
    const float b3 = np_block128_sq(p + 384);
    return __fadd_rn(__fadd_rn(b0, b1), __fadd_rn(b2, b3));
}
// exact einsum dot, numpy SSE 4-chain order (validated)
__device__ __forceinline__ float np_dot_512(const float* r, const float* w) {
    float a0 = 0.f, a1 = 0.f, a2 = 0.f, a3 = 0.f;
    for (int ko = 0; ko < 512; ko += 8) {
        a0 = __fadd_rn(a0, __fmul_rn(r[ko + 0], w[ko + 0]));
        a1 = __fadd_rn(a1, __fmul_rn(r[ko + 1], w[ko + 1]));
        a2 = __fadd_rn(a2, __fmul_rn(r[ko + 2], w[ko + 2]));
        a3 = __fadd_rn(a3, __fmul_rn(r[ko + 3], w[ko + 3]));
        a0 = __fadd_rn(a0, __fmul_rn(r[ko + 4], w[ko + 4]));
        a1 = __fadd_rn(a1, __fmul_rn(r[ko + 5], w[ko + 5]));
        a2 = __fadd_rn(a2, __fmul_rn(r[ko + 6], w[ko + 6]));
        a3 = __fadd_rn(a3, __fmul_rn(r[ko + 7], w[ko + 7]));
    }
    return __fadd_rn(__fadd_rn(a0, a2), __fadd_rn(a1, a3));
}

__global__ __launch_bounds__(64) void rvq_init(double* lossws) {
    if (threadIdx.x < QQ) lossws[threadIdx.x] = 0.0;
}

__global__ __launch_bounds__(256) void rvq_cnorm(const float* __restrict__ cbs,
                                                 float* __restrict__ cnorm) {
    const int gid = blockIdx.x * 256 + threadIdx.x;
    cnorm[gid] = np_sum_sq_512(cbs + (size_t)gid * DD);
}

// Residual VQ argmin: FMA approx bulk + exact (numpy-semantics) re-check of near-min.
__global__ __launch_bounds__(256, 4) void rvq_argmin(const float* __restrict__ z,
                                                     const float* __restrict__ cbs,
                                                     const float* __restrict__ cnorm,
                                                     int* __restrict__ codes_ws) {
    __shared__ float resid[MM * RS];
    __shared__ float A_sh[MM];
    __shared__ int   sel[MM];
    __shared__ float wmin[4][8];
    __shared__ float amin_sh[MM];
    __shared__ unsigned long long cand_sh[MM];

    const int tid = threadIdx.x;
    const int blk = blockIdx.x;
    const int b   = blk >> 7;
    const int t0  = (blk & 127) * MM;
    const float* zb = z + (size_t)b * DD * TT + t0;

    for (int p = 0; p < 32; ++p) {
        const int d = (tid >> 4) + p * 16;
        const int m = tid & 15;
        resid[m * RS + d] = zb[(size_t)d * TT + m];
    }
    __syncthreads();
    if (tid < MM) A_sh[tid] = np_sum_sq_512(resid + tid * RS);

    const int half  = tid >> 7;
    const int nl    = tid & 127;
    const int mbase = half * 8;
    const int wv    = tid >> 6;
    const float* rb = resid + mbase * RS;

    for (int q = 0; q < QQ; ++q) {
        __syncthreads();                 // resid & A_sh stable for this stage
        const float* cbq = cbs + (size_t)q * NN * DD;

        float Af[8];
        #pragma unroll
        for (int mm = 0; mm < 8; ++mm) Af[mm] = A_sh[mbase + mm];

        float v1[8], v2[8]; int n1[8], n2[8];
        #pragma unroll
        for (int mm = 0; mm < 8; ++mm) { v1[mm] = FLT_MAX; v2[mm] = FLT_MAX; n1[mm] = 0; n2[mm] = 0; }

        for (int ch = 0; ch < 4; ++ch) {
            const int na = ch * 256 + nl;          // codeword A
            const int nb2 = na + 128;              // codeword B
            const float* cA = cbq + (size_t)na * DD;
            const float* cB = cbq + (size_t)nb2 * DD;

            float4 acc[8][2];
            #pragma unroll
            for (int mm = 0; mm < 8; ++mm) {
                acc[mm][0] = make_float4(0.f, 0.f, 0.f, 0.f);
                acc[mm][1] = make_float4(0.f, 0.f, 0.f, 0.f);
            }

            #pragma unroll 2
            for (int k8 = 0; k8 < 64; ++k8) {
                const int ko = k8 * 8;
                const float4 wa0 = *(const float4*)(cA + ko);
                const float4 wa1 = *(const float4*)(cA + ko + 4);
                const float4 wb0 = *(const float4*)(cB + ko);
                const float4 wb1 = *(const float4*)(cB + ko + 4);
                #pragma unroll
                for (int mm = 0; mm < 8; ++mm) {
                    const float4 r0 = *(const float4*)(rb + mm * RS + ko);
                    const float4 r1 = *(const float4*)(rb + mm * RS + ko + 4);
                    // approx pass: FMA contraction welcome
                    acc[mm][0].x += r0.x * wa0.x; acc[mm][0].y += r0.y * wa0.y;
                    acc[mm][0].z += r0.z * wa0.z; acc[mm][0].w += r0.w * wa0.w;
                    acc[mm][0].x += r1.x * wa1.x; acc[mm][0].y += r1.y * wa1.y;
                    acc[mm][0].z += r1.z * wa1.z; acc[mm][0].w += r1.w * wa1.w;
                    acc[mm][1].x += r0.x * wb0.x; acc[mm][1].y += r0.y * wb0.y;
                    acc[mm][1].z += r0.z * wb0.z; acc[mm][1].w += r0.w * wb0.w;
                    acc[mm][1].x += r1.x * wb1.x; acc[mm][1].y += r1.y * wb1.y;
                    acc[mm][1].z += r1.z * wb1.z; acc[mm][1].w += r1.w * wb1.w;
                }
            }
            const float CnA = cnorm[q * NN + na];
            const float CnB = cnorm[q * NN + nb2];
            #pragma unroll
            for (int mm = 0; mm < 8; ++mm) {
                const float4 aA = acc[mm][0];
                const float4 aB = acc[mm][1];
                const float EA = (aA.x + aA.z) + (aA.y + aA.w);
                const float EB = (aB.x + aB.z) + (aB.y + aB.w);
                const float sA = (Af[mm] - 2.0f * EA) + CnA;
                const float sB = (Af[mm] - 2.0f * EB) + CnB;
                if (sA < v1[mm])      { v2[mm] = v1[mm]; n2[mm] = n1[mm]; v1[mm] = sA; n1[mm] = na; }
                else if (sA < v2[mm]) { v2[mm] = sA; n2[mm] = na; }
                if (sB < v1[mm])      { v2[mm] = v1[mm]; n2[mm] = n1[mm]; v1[mm] = sB; n1[mm] = nb2; }
                else if (sB < v2[mm]) { v2[mm] = sB; n2[mm] = nb2; }
            }
        }

        // per-wave approx-min per m, then block combine
        #pragma unroll
        for (int mm = 0; mm < 8; ++mm) {
            float v = v1[mm];
            #pragma unroll
            for (int mask = 1; mask < 64; mask <<= 1) {
                const float o = __shfl_xor(v, mask, 64);
                v = o < v ? o : v;
            }
            if ((tid & 63) == 0) wmin[wv][mm] = v;
        }
        __syncthreads();
        if (tid < MM) {
            const int h2 = tid >> 3;
            amin_sh[tid] = fminf(wmin[h2 * 2][tid & 7], wmin[h2 * 2 + 1][tid & 7]);
            cand_sh[tid] = 0xFFFFFFFFFFFFFFFFull;
        }
        __syncthreads();

        // exact re-check of near-min candidates (validated numpy arithmetic)
        #pragma unroll
        for (int mm = 0; mm < 8; ++mm) {
            const int mg = mbase + mm;
            const float thr = amin_sh[mg] + MARGIN;
            if (v2[mm] <= thr) {
                // rare: 2+ of this thread's candidates near min -> exact-score all 8
                #pragma unroll
                for (int ch = 0; ch < 4; ++ch)
                    #pragma unroll
                    for (int cw = 0; cw < 2; ++cw) {
                        const int n = ch * 256 + cw * 128 + nl;
                        const float E = np_dot_512(resid + mg * RS, cbq + (size_t)n * DD);
                        const float s = __fadd_rn(__fsub_rn(Af[mm], __fmul_rn(2.0f, E)),
                                                  cnorm[q * NN + n]);
                        const unsigned long long pk =
                            ((unsigned long long)__float_as_uint(s) << 32) | (unsigned)n;
                        atomicMin(&cand_sh[mg], pk);
                    }
            } else if (v1[mm] <= thr) {
                const int n = n1[mm];
                const float E = np_dot_512(resid + mg * RS, cbq + (size_t)n * DD);
                const float s = __fadd_rn(__fsub_rn(Af[mm], __fmul_rn(2.0f, E)),
                                          cnorm[q * NN + n]);
                const unsigned long long pk =
                    ((unsigned long long)__float_as_uint(s) << 32) | (unsigned)n;
                atomicMin(&cand_sh[mg], pk);
            }
        }
        __syncthreads();
        if (tid < MM) {
            const int ix = (int)(cand_sh[tid] & 0x3FF);
            sel[tid] = ix;
            codes_ws[b * QQ * TT + q * TT + t0 + tid] = ix;
        }
        __syncthreads();

        if (q < QQ - 1) {
            const int m = tid >> 4, l16 = tid & 15;
            const float* cr = cbq + (size_t)sel[m] * DD;
            for (int jj = 0; jj < 32; ++jj) {
                const int d = l16 + jj * 16;
                resid[m * RS + d] = __fsub_rn(resid[m * RS + d], cr[d]);
            }
            __syncthreads();
            if (tid < MM) A_sh[tid] = np_sum_sq_512(resid + tid * RS);
        }
    }
}

// Rebuild: quantized = sequential fp32 sum of chosen codewords (np order),
// codes as float, per-stage loss partials. (validated)
__global__ __launch_bounds__(256) void rvq_build(const float* __restrict__ z,
                                                 const float* __restrict__ cbs,
                                                 const int* __restrict__ codes_ws,
                                                 float* __restrict__ out,
                                                 double* __restrict__ lossws) {
    __shared__ int    lcode[MM * QQ];
    __shared__ double lpart[4][QQ];

    const int tid = threadIdx.x;
    const int blk = blockIdx.x;
    const int b   = blk >> 7;
    const int t0  = (blk & 127) * MM;

    if (tid < MM * QQ) {
        const int m = tid >> 3;
        const int q = tid & 7;
        const int c = codes_ws[b * QQ * TT + q * TT + t0 + m];
        lcode[tid] = c;
        out[(size_t)BB * DD * TT + (size_t)b * QQ * TT + (size_t)q * TT + t0 + m] = (float)c;
    }
    __syncthreads();

    const int m  = tid & 15;
    const int dl = tid >> 4;

    double lsum[QQ];
    #pragma unroll
    for (int q = 0; q < QQ; ++q) lsum[q] = 0.0;

    for (int p = 0; p < DD / 16; ++p) {
        const int d = dl + p * 16;
        float r  = z[(size_t)b * DD * TT + (size_t)d * TT + t0 + m];
        float qa = 0.0f;
        #pragma unroll
        for (int q = 0; q < QQ; ++q) {
            const float c = cbs[(size_t)q * NN * DD + (size_t)lcode[m * 8 + q] * DD + d];
            qa = __fadd_rn(qa, c);
            r  = __fsub_rn(r, c);
            lsum[q] += (double)r * (double)r;
        }
        out[(size_t)b * DD * TT + (size_t)d * TT + t0 + m] = qa;
    }

    const int wid = tid >> 6, lane = tid & 63;
    #pragma unroll
    for (int q = 0; q < QQ; ++q) {
        double v = lsum[q];
        #pragma unroll
        for (int off = 32; off > 0; off >>= 1) v += __shfl_down(v, off, 64);
        lsum[q] = v;
    }
    if (lane == 0) {
        #pragma unroll
        for (int q = 0; q < QQ; ++q) lpart[wid][q] = lsum[q];
    }
    __syncthreads();
    if (tid < QQ) {
        const double s = lpart[0][tid] + lpart[1][tid] + lpart[2][tid] + lpart[3][tid];
        atomicAdd(&lossws[tid], s);
    }
}

__global__ __launch_bounds__(64) void rvq_final(const double* __restrict__ lossws,
                                                float* __restrict__ out) {
    if (threadIdx.x == 0) {
        double tot = 0.0;
        for (int q = 0; q < QQ; ++q) {
            double c = lossws[q] / (double)((size_t)BB * TT * DD);
            c = c < 0.0 ? 0.0 : (c > 10.0 ? 10.0 : c);
            tot += 0.25 * c;
        }
        tot = tot < 0.0 ? 0.0 : (tot > 10.0 ? 10.0 : tot);
        out[(size_t)BB * DD * TT + (size_t)BB * QQ * TT] = (float)tot;
    }
}

extern "C" void kernel_launch(void* const* d_in, const int* in_sizes, int n_in,
                              void* d_out, int out_size, void* d_ws, size_t ws_size,
                              hipStream_t stream) {
    const float* z   = (const float*)d_in[0];
    const float* cbs = (const float*)d_in[1];
    float* out       = (float*)d_out;
    double* lossws   = (double*)d_ws;
    float* cnorm     = (float*)((char*)d_ws + 64);
    int* codes_ws    = (int*)((char*)d_ws + 64 + QQ * NN * 4);

    rvq_init  <<<1, 64, 0, stream>>>(lossws);
    rvq_cnorm <<<QQ * NN / 256, 256, 0, stream>>>(cbs, cnorm);
    rvq_argmin<<<BB * (TT / MM), 256, 0, stream>>>(z, cbs, cnorm, codes_ws);
    rvq_build <<<BB * (TT / MM), 256, 0, stream>>>(z, cbs, codes_ws, out, lossws);
    rvq_final <<<1, 64, 0, stream>>>(lossws, out);
}